// Round 11
// baseline (388.687 us; speedup 1.0000x reference)
//
#include <hip/hip_runtime.h>
#include <math.h>

#define NN 50000
#define EE 300000
#define NG 8                   // 7 softmax GATs + 1 plain (sin); g' order: tgt-contiguous
#define NBKT 782               // buckets of 64 nodes (512 keys = 64 nodes x 8 gats)
#define BCAP 3584              // slots per bucket (mean 3072, sigma~55 -> 9 sigma margin)
#define TILE 1024              // edges per etype per binA block
#define NBLKE ((EE + TILE - 1) / TILE)   // 293

typedef unsigned short u16;
typedef unsigned int u32;
typedef short bf16x8 __attribute__((ext_vector_type(8)));
typedef float f32x16 __attribute__((ext_vector_type(16)));

__device__ __forceinline__ float b2f(u16 u) { return __uint_as_float(((u32)u) << 16); }
__device__ __forceinline__ u16 f2b(float f) {
    u32 x = __float_as_uint(f);
    u32 lsb = (x >> 16) & 1u;
    return (u16)((x + 0x7fffu + lsb) >> 16);
}

// stub symbol kept
__global__ void HeteroGATLayer_14259291423309_kernel() {}

// ---------------- setup: zero gcur + zij constants ----------------
struct SetupP {
    int* gcur;
    const float* attn[3]; const float* fcW[3]; const float* fcb[3];
    float* consts;
};

__global__ __launch_bounds__(256) void k_setup(SetupP p) {
    const int i = blockIdx.x * 256 + threadIdx.x;
    if (i < NBKT) p.gcur[i] = 0;
    if (blockIdx.x == 3) {
        const int z = threadIdx.x >> 6, lane = threadIdx.x & 63;
        if (z < 3) {
            float a2 = p.attn[z][128 + lane];
            float x = p.fcW[z][lane] * a2;
            float y = p.fcb[z][lane] * a2;
            #pragma unroll
            for (int off = 32; off; off >>= 1) {
                x += __shfl_down(x, off);
                y += __shfl_down(y, off);
            }
            if (lane == 0) {
                // consts slots by g': g'0 temporal -> 0,1 ; g'4 ttr -> 8,9 ; g'1 rut -> 2,3
                const int co[3] = {0, 8, 2};
                p.consts[co[z]] = x;
                p.consts[co[z] + 1] = y;
            }
        }
    }
}

// ---------------- projections via MFMA + fused attention dots ----------------
struct ProjP {
    const float* feat[3];
    const float* W[8]; const float* b[8];
    u16* wh;                    // Wh arena base
    int ntile[3]; int tiles[3][4];
    int nvec[8];
    const float* avec[8][4];    // attention sub-vector (64 floats)
    float* dvec[8][4];          // destination (el/er + g'*NN)
};

__global__ __launch_bounds__(256) void k_proj(ProjP p) {
    __shared__ u16 sA[64 * 64];      // feat tile (persistent)
    __shared__ u16 sW[64 * 64];      // weight tile
    __shared__ u16 sC[64 * 66];      // C tile, padded stride
    const int f = blockIdx.y;
    const int tid = threadIdx.x;
    const int row0 = blockIdx.x * 64;
    const float* feat = p.feat[f];

    #pragma unroll
    for (int q = 0; q < 4; ++q) {
        int idx = q * 256 + tid;
        int r = idx >> 4;
        int c4 = (idx & 15) * 4;
        int gr = row0 + r;
        if (gr >= NN) gr = NN - 1;
        float4 fv = *(const float4*)(feat + (size_t)gr * 64 + c4);
        *(ushort4*)&sA[r * 64 + c4] = make_ushort4(f2b(fv.x), f2b(fv.y), f2b(fv.z), f2b(fv.w));
    }

    const int wv = tid >> 6, lane = tid & 63;
    const int mrow = (wv & 1) * 32, ncol = (wv >> 1) * 32;
    const int half = lane >> 5, l31 = lane & 31;
    const int nt = p.ntile[f];

    for (int ti = 0; ti < nt; ++ti) {
        const int t = p.tiles[f][ti];
        const float* W = p.W[t];
        #pragma unroll
        for (int q = 0; q < 4; ++q) {
            int idx = q * 256 + tid;
            int r = idx >> 4;
            int c4 = (idx & 15) * 4;
            float4 wv4 = *(const float4*)(W + r * 64 + c4);
            *(ushort4*)&sW[r * 64 + c4] = make_ushort4(f2b(wv4.x), f2b(wv4.y), f2b(wv4.z), f2b(wv4.w));
        }
        __syncthreads();    // sA/sW staged; prev iteration's dots (sC reads) done

        f32x16 acc;
        #pragma unroll
        for (int i = 0; i < 16; ++i) acc[i] = 0.0f;
        #pragma unroll
        for (int k0 = 0; k0 < 64; k0 += 16) {
            bf16x8 af = *(const bf16x8*)&sA[(mrow + l31) * 64 + k0 + half * 8];
            bf16x8 bf = *(const bf16x8*)&sW[(ncol + l31) * 64 + k0 + half * 8];
            acc = __builtin_amdgcn_mfma_f32_32x32x16_bf16(af, bf, acc, 0, 0, 0);
        }

        float bb = p.b[t][ncol + l31];
        u16* whp = p.wh + (size_t)t * NN * 64;
        #pragma unroll
        for (int reg = 0; reg < 16; ++reg) {
            int rowD = (reg & 3) + 8 * (reg >> 2) + 4 * half;
            int gr = row0 + mrow + rowD;
            u16 c16 = f2b(acc[reg] + bb);
            if (gr < NN) whp[(size_t)gr * 64 + ncol + l31] = c16;
            sC[(mrow + rowD) * 66 + ncol + l31] = c16;
        }
        __syncthreads();    // sC complete

        // fused attention dots: thread = (row r, vec j); 64 FMA each
        const int r = tid & 63, j = tid >> 6;
        if (j < p.nvec[t]) {
            const float* av = p.avec[t][j];
            float s = 0.f;
            #pragma unroll
            for (int c = 0; c < 64; c += 4) {
                ushort4 cv = *(const ushort4*)&sC[r * 66 + c];
                float4 a4 = *(const float4*)(av + c);
                s += b2f(cv.x) * a4.x + b2f(cv.y) * a4.y + b2f(cv.z) * a4.z + b2f(cv.w) * a4.w;
            }
            int gr = row0 + r;
            if (gr < NN) p.dvec[t][j][gr] = s;
        }
    }
}

// ---------------- binA: all-8-etype LDS-histogram binning, key = dst*8+g' ---------------
// payload: {arena byte off of src Wh row, f32 raw exp score, f32 sc*w, (dst&63)*8+g}
struct BinAP {
    const int* src[8]; const int* dst[8]; const float* w[8];
    const float* el[8]; const float* er[8];
    const float* consts;
    int whoff[8];
    int* gcur; int4* bkt;
};

__global__ __launch_bounds__(512) void k_binA(BinAP p) {
    __shared__ int hist[784];
    const int tid = threadIdx.x;
    const int e = blockIdx.x * TILE + tid * 2;   // 2 edges/thread/etype
    for (int i = tid; i < 784; i += 512) hist[i] = 0;
    const bool valid = e < EE;                   // EE even -> e+1 also in range
    int d0[8], d1[8];
    __syncthreads();
    // phase A: histogram over 782 buckets (all 8 etypes), keep dst in regs
    #pragma unroll
    for (int g = 0; g < 8; ++g) {
        int2 dv = valid ? *(const int2*)(p.dst[g] + e) : make_int2(0, 0);
        d0[g] = dv.x; d1[g] = dv.y;
        if (valid) {
            atomicAdd(&hist[dv.x >> 6], 1);
            atomicAdd(&hist[dv.y >> 6], 1);
        }
    }
    __syncthreads();
    // phase B: one global atomic per (block,bucket); hist becomes write cursor
    for (int b = tid; b < NBKT; b += 512) {
        int c = hist[b];
        hist[b] = c ? atomicAdd(&p.gcur[b], c) : 0;
    }
    __syncthreads();
    // phase C: payload + clustered write (avg 10.5 consecutive slots per bucket per block)
    #pragma unroll
    for (int g = 0; g < 8; ++g) {
        if (!valid) continue;
        int2 sv = *(const int2*)(p.src[g] + e);
        const float* wp = p.w[g];
        const bool hw = wp != 0;
        float2 wv = hw ? *(const float2*)(wp + e) : make_float2(0.f, 0.f);
        float c1 = 0.f, c0 = 0.f;
        if (g < 7 && hw) { c1 = p.consts[2 * g]; c0 = p.consts[2 * g + 1]; }
        const int wo = p.whoff[g];
        int ss[2] = {sv.x, sv.y};
        int dd[2] = {d0[g], d1[g]};
        float ww[2] = {wv.x, wv.y};
        #pragma unroll
        for (int q = 0; q < 2; ++q) {
            float sc = 1.0f, pw = 0.0f;
            if (g < 7) {
                sc = p.el[g][ss[q]] + p.er[g][dd[q]];
                if (hw) sc += c1 * ww[q] + c0;
                sc = sc > 0.f ? sc : 0.2f * sc;       // leaky_relu(0.2)
                sc = __expf(sc);
                if (hw) pw = sc * ww[q];
            }
            int bkt_i = dd[q] >> 6;
            int pos = atomicAdd(&hist[bkt_i], 1);
            int4 v;
            v.x = wo + (ss[q] << 7);
            v.y = __float_as_int(sc);
            v.z = __float_as_int(pw);
            v.w = ((dd[q] & 63) << 3) | g;
            p.bkt[(size_t)bkt_i * BCAP + pos] = v;
        }
    }
}

// ---------------- bg: fused counting sort + softmax + gather + ReLU + output ------------
// bucket = 64 nodes x 8 gats. After sort, node n's slots are contiguous per target:
// task = keys n8..n8+1, worker = n8+2..n8+4, state = n8+5..n8+7 (g' ordering).
struct BgP {
    const float* fcW[3]; const float* fcb[3];   // 0: temporal fc, 1: ttr fc, 2: rut fc
};

// masked 4-slot step: slots beyond len contribute 0 (off masked to row 0, alpha to 0)
#define BGSTEP4(t, baseV, lenV)                                                    \
    {                                                                              \
        int2 e0 = st2[baseV + k], e1 = st2[baseV + k + 1];                         \
        int2 e2 = st2[baseV + k + 2], e3 = st2[baseV + k + 3];                     \
        int o0 = (k < lenV) ? e0.x : 0;                                            \
        int o1 = (k + 1 < lenV) ? e1.x : 0;                                        \
        int o2 = (k + 2 < lenV) ? e2.x : 0;                                        \
        int o3 = (k + 3 < lenV) ? e3.x : 0;                                        \
        float f0 = (k < lenV) ? __int_as_float(e0.y) : 0.f;                        \
        float f1 = (k + 1 < lenV) ? __int_as_float(e1.y) : 0.f;                    \
        float f2 = (k + 2 < lenV) ? __int_as_float(e2.y) : 0.f;                    \
        float f3 = (k + 3 < lenV) ? __int_as_float(e3.y) : 0.f;                    \
        u32 w0 = *(const u32*)(whA + (u32)(o0 + dby));                             \
        u32 w1 = *(const u32*)(whA + (u32)(o1 + dby));                             \
        u32 w2 = *(const u32*)(whA + (u32)(o2 + dby));                             \
        u32 w3 = *(const u32*)(whA + (u32)(o3 + dby));                             \
        a0[t] += f0 * b2f((u16)w0); a1[t] += f0 * b2f((u16)(w0 >> 16));            \
        a0[t] += f1 * b2f((u16)w1); a1[t] += f1 * b2f((u16)(w1 >> 16));            \
        a0[t] += f2 * b2f((u16)w2); a1[t] += f2 * b2f((u16)(w2 >> 16));            \
        a0[t] += f3 * b2f((u16)w3); a1[t] += f3 * b2f((u16)(w3 >> 16));            \
    }

__global__ __launch_bounds__(512) void k_bg(BgP p, const int* __restrict__ gcur,
        const int4* __restrict__ bkt, const char* __restrict__ whA,
        float* __restrict__ out) {
    __shared__ int2 st2[BCAP + 128];   // sorted {arena_off, alpha}; +128 masked-read pad
    __shared__ float st3[BCAP];        // sorted pw
    __shared__ int hist[512];
    __shared__ int scn[512];
    __shared__ float sSw[512];
    __shared__ int wsum[8];
    const int b = blockIdx.x;
    const int tid = threadIdx.x;
    int count = gcur[b];
    if (count > BCAP) count = BCAP;
    hist[tid] = 0;
    __syncthreads();
    const int4* src = bkt + (size_t)b * BCAP;
    for (int i = tid; i < count; i += 512) atomicAdd(&hist[src[i].w], 1);
    __syncthreads();
    // shuffle-based exclusive scan of 512 counts
    int h = hist[tid];
    const int lane = tid & 63, wvi = tid >> 6;
    int incl = h;
    #pragma unroll
    for (int off = 1; off < 64; off <<= 1) {
        int t = __shfl_up(incl, off);
        if (lane >= off) incl += t;
    }
    if (lane == 63) wsum[wvi] = incl;
    __syncthreads();
    int wb = 0;
    #pragma unroll
    for (int w = 0; w < 8; ++w)
        if (w < wvi) wb += wsum[w];
    const int excl = wb + incl - h;
    scn[tid] = excl;
    __syncthreads();
    // scatter sorted into LDS
    for (int i = tid; i < count; i += 512) {
        int4 v = src[i];
        int pos = atomicAdd(&scn[v.w], 1);
        st2[pos] = make_int2(v.x, v.y);
        st3[pos] = __int_as_float(v.z);
    }
    __syncthreads();
    // per-key: den/sw sums, then pre-scale alpha = sc * inv in place (own segment)
    float den = 0.f, sw = 0.f;
    for (int j = 0; j < h; ++j) {
        den += __int_as_float(st2[excl + j].y);
        sw += st3[excl + j];
    }
    const int gk = tid & 7;
    float inv = (gk == 7) ? 1.0f : ((h > 0 && den > 0.f) ? 1.0f / den : 0.f);
    sSw[tid] = sw * inv;
    for (int j = 0; j < h; ++j)
        st2[excl + j].y = __float_as_int(__int_as_float(st2[excl + j].y) * inv);
    __syncthreads();
    // gather: 8 waves x 2 nodes/wave x 4 passes = 64 nodes
    const int half = lane >> 5, c = lane & 31;
    const int dby = c * 4;
    for (int pass = 0; pass < 4; ++pass) {
        const int nl = pass * 16 + wvi * 2 + half;
        const int n8 = nl * 8;
        // per-target contiguous ranges (scn post-scatter = segment end)
        int bT = scn[n8] - hist[n8];
        int eT = scn[n8 + 1];
        int eW = scn[n8 + 4];
        int eS = scn[n8 + 7];
        int lT = eT - bT, lW = eW - eT, lS = eS - eW;
        int lTa = __builtin_amdgcn_readlane(lT, 0), lTb = __builtin_amdgcn_readlane(lT, 32);
        int lWa = __builtin_amdgcn_readlane(lW, 0), lWb = __builtin_amdgcn_readlane(lW, 32);
        int lSa = __builtin_amdgcn_readlane(lS, 0), lSb = __builtin_amdgcn_readlane(lS, 32);
        int lTm = lTa > lTb ? lTa : lTb;
        int lWm = lWa > lWb ? lWa : lWb;
        int lSm = lSa > lSb ? lSa : lSb;
        int kmax = lTm > lWm ? lTm : lWm;
        kmax = kmax > lSm ? kmax : lSm;

        float a0[3] = {0.f, 0.f, 0.f}, a1[3] = {0.f, 0.f, 0.f};
        for (int k = 0; k < kmax; k += 4) {
            if (k < lTm) BGSTEP4(0, bT, lT)
            if (k < lWm) BGSTEP4(1, eT, lW)
            if (k < lSm) BGSTEP4(2, eW, lS)
        }

        float tT0 = a0[0], tT1 = a1[0];
        if (hist[n8] > 0) {        // temporal fc
            float2 fw = *(const float2*)(p.fcW[0] + 2 * c);
            float2 fb = *(const float2*)(p.fcb[0] + 2 * c);
            float s = sSw[n8];
            tT0 += fw.x * s + fb.x; tT1 += fw.y * s + fb.y;
        }
        if (hist[n8 + 1] > 0) {    // rut fc
            float2 fw = *(const float2*)(p.fcW[2] + 2 * c);
            float2 fb = *(const float2*)(p.fcb[2] + 2 * c);
            float s = sSw[n8 + 1];
            tT0 += fw.x * s + fb.x; tT1 += fw.y * s + fb.y;
        }
        float tW0 = a0[1], tW1 = a1[1];
        if (hist[n8 + 4] > 0) {    // ttr fc
            float2 fw = *(const float2*)(p.fcW[1] + 2 * c);
            float2 fb = *(const float2*)(p.fcb[1] + 2 * c);
            float s = sSw[n8 + 4];
            tW0 += fw.x * s + fb.x; tW1 += fw.y * s + fb.y;
        }
        float tS0 = a0[2], tS1 = a1[2];

        const int gnode = b * 64 + nl;
        if (gnode < NN) {
            float2 o;
            o.x = tT0 > 0.f ? tT0 : 0.f; o.y = tT1 > 0.f ? tT1 : 0.f;
            *(float2*)(out + ((size_t)0 * NN + gnode) * 64 + 2 * c) = o;
            o.x = tW0 > 0.f ? tW0 : 0.f; o.y = tW1 > 0.f ? tW1 : 0.f;
            *(float2*)(out + ((size_t)1 * NN + gnode) * 64 + 2 * c) = o;
            o.x = tS0 > 0.f ? tS0 : 0.f; o.y = tS1 > 0.f ? tS1 : 0.f;
            *(float2*)(out + ((size_t)2 * NN + gnode) * 64 + 2 * c) = o;
        }
    }
}

extern "C" void kernel_launch(void* const* d_in, const int* in_sizes, int n_in,
                              void* d_out, int out_size, void* d_ws, size_t ws_size,
                              hipStream_t stream) {
    (void)in_sizes; (void)n_in; (void)out_size; (void)ws_size;
    const float* feats[3] = {(const float*)d_in[0], (const float*)d_in[1], (const float*)d_in[2]};
    const int* srcs[8];
    const int* dsts[8];
    for (int t = 0; t < 8; ++t) {
        srcs[t] = (const int*)d_in[3 + 2 * t];
        dsts[t] = (const int*)d_in[4 + 2 * t];
    }
    const float* ew0 = (const float*)d_in[19];
    const float* ew1 = (const float*)d_in[20];
    const float* ew2 = (const float*)d_in[21];
    const float* Wm[8];
    const float* bm[8];
    for (int t = 0; t < 8; ++t) {
        Wm[t] = (const float*)d_in[22 + 2 * t];
        bm[t] = (const float*)d_in[23 + 2 * t];
    }
    const float* fcW0 = (const float*)d_in[38];
    const float* fcb0 = (const float*)d_in[39];
    const float* fcW1 = (const float*)d_in[40];
    const float* fcb1 = (const float*)d_in[41];
    const float* fcW2 = (const float*)d_in[42];
    const float* fcb2 = (const float*)d_in[43];
    const float* attn_W          = (const float*)d_in[44];
    const float* attn_ttr_W      = (const float*)d_in[45];
    const float* attn_rut_W      = (const float*)d_in[46];
    const float* attn_assigned_W = (const float*)d_in[47];
    const float* attn_com_W      = (const float*)d_in[48];
    const float* attn_tin_W      = (const float*)d_in[49];
    const float* attn_rin_W      = (const float*)d_in[50];

    // ---- workspace (~100 MB): Wh 51.2 | el/er 2.8 | consts | gcur | bkt 44.8
    u16* Wh = (u16*)d_ws;
    char* b0 = (char*)d_ws + (size_t)8 * NN * 64 * sizeof(u16);
    float* el     = (float*)b0;
    float* er     = el + (size_t)7 * NN;
    float* consts = er + (size_t)7 * NN;
    int* gcur     = (int*)(consts + 16);
    int4* bkt     = (int4*)(((size_t)(gcur + NBKT) + 15) & ~(size_t)15);

    // g' order (target-contiguous): 0 temporal, 1 rut | 2 assigned, 3 com, 4 ttr |
    //                               5 tin, 6 win, 7 sin
    int g_et[8]   = {0, 7, 1, 2, 6, 3, 4, 5};    // etype index per g'
    int g_sidx[8] = {0, 7, 1, 2, 6, 3, 4, 5};    // src Wh tile per g'
    const float* g_w[8] = {ew0, ew2, 0, 0, ew1, 0, 0, 0};

    // 1) setup: zero gcur + zij constants
    {
        SetupP sp;
        sp.gcur = gcur;
        sp.attn[0] = attn_W;     sp.fcW[0] = fcW0; sp.fcb[0] = fcb0;
        sp.attn[1] = attn_ttr_W; sp.fcW[1] = fcW1; sp.fcb[1] = fcb1;
        sp.attn[2] = attn_rut_W; sp.fcW[2] = fcW2; sp.fcb[2] = fcb2;
        sp.consts = consts;
        k_setup<<<4, 256, 0, stream>>>(sp);
    }

    // 2) projections (MFMA) + fused el/er dots (el/er indexed by g')
    {
        ProjP pp;
        pp.feat[0] = feats[0]; pp.feat[1] = feats[1]; pp.feat[2] = feats[2];
        for (int t = 0; t < 8; ++t) { pp.W[t] = Wm[t]; pp.b[t] = bm[t]; }
        pp.wh = Wh;
        pp.ntile[0] = 4; pp.tiles[0][0] = 0; pp.tiles[0][1] = 1; pp.tiles[0][2] = 3; pp.tiles[0][3] = 6;
        pp.ntile[1] = 3; pp.tiles[1][0] = 2; pp.tiles[1][1] = 4; pp.tiles[1][2] = 7; pp.tiles[1][3] = 0;
        pp.ntile[2] = 1; pp.tiles[2][0] = 5; pp.tiles[2][1] = 0; pp.tiles[2][2] = 0; pp.tiles[2][3] = 0;
        for (int t = 0; t < 8; ++t) {
            pp.nvec[t] = 0;
            for (int j = 0; j < 4; ++j) { pp.avec[t][j] = 0; pp.dvec[t][j] = 0; }
        }
        auto setv = [&](int t, int j, const float* a, float* dv) { pp.avec[t][j] = a; pp.dvec[t][j] = dv; };
        // tile -> dot vectors; el[g'] = src-tile dot, er[g'] = dst-tile dot
        pp.nvec[0] = 3; setv(0, 0, attn_W, el + 0 * NN);            // el g'0
                        setv(0, 1, attn_W + 64, er + 0 * NN);       // er g'0
                        setv(0, 2, attn_rut_W + 64, er + 1 * NN);   // er g'1 (rut dst = task)
        pp.nvec[1] = 1; setv(1, 0, attn_assigned_W, el + 2 * NN);   // el g'2
        pp.nvec[2] = 4; setv(2, 0, attn_com_W, el + 3 * NN);        // el g'3
                        setv(2, 1, attn_assigned_W + 64, er + 2 * NN);
                        setv(2, 2, attn_com_W + 64, er + 3 * NN);
                        setv(2, 3, attn_ttr_W + 64, er + 4 * NN);
        pp.nvec[3] = 1; setv(3, 0, attn_tin_W, el + 5 * NN);        // el g'5
        pp.nvec[4] = 1; setv(4, 0, attn_rin_W, el + 6 * NN);        // el g'6
        pp.nvec[5] = 2; setv(5, 0, attn_tin_W + 64, er + 5 * NN);
                        setv(5, 1, attn_rin_W + 64, er + 6 * NN);
        pp.nvec[6] = 1; setv(6, 0, attn_ttr_W, el + 4 * NN);        // el g'4
        pp.nvec[7] = 1; setv(7, 0, attn_rut_W, el + 1 * NN);        // el g'1
        k_proj<<<dim3(782, 3), 256, 0, stream>>>(pp);
    }

    // 3) binA: bucketed payload build, all 8 etypes per block
    {
        BinAP bp;
        for (int g = 0; g < 8; ++g) {
            bp.src[g] = srcs[g_et[g]];
            bp.dst[g] = dsts[g_et[g]];
            bp.w[g] = g_w[g];
            bp.el[g] = (g < 7) ? el + (size_t)g * NN : 0;
            bp.er[g] = (g < 7) ? er + (size_t)g * NN : 0;
            bp.whoff[g] = g_sidx[g] * NN * 128;     // byte offset of gat's Wh tile
        }
        bp.consts = consts;
        bp.gcur = gcur;
        bp.bkt = bkt;
        k_binA<<<NBLKE, 512, 0, stream>>>(bp);
    }

    // 4) bg: fused sort + softmax + gather + ReLU + output
    {
        BgP gp;
        gp.fcW[0] = fcW0; gp.fcb[0] = fcb0;
        gp.fcW[1] = fcW1; gp.fcb[1] = fcb1;
        gp.fcW[2] = fcW2; gp.fcb[2] = fcb2;
        k_bg<<<NBKT, 512, 0, stream>>>(gp, gcur, bkt, (const char*)Wh, (float*)d_out);
    }
}

// Round 12
// 387.684 us; speedup vs baseline: 1.0026x; 1.0026x over previous
//
#include <hip/hip_runtime.h>
#include <math.h>

#define NN 50000
#define EE 300000
#define NG 8                   // 7 softmax GATs + 1 plain (sin); g' order: tgt-contiguous
#define NBKT 782               // buckets of 64 nodes (512 keys = 64 nodes x 8 gats)
#define BCAP 3584              // slots per bucket (mean 3072, sigma~55 -> 9 sigma margin)
#define TILE 1024              // edges per etype per binA block
#define NBLKE ((EE + TILE - 1) / TILE)   // 293

typedef unsigned short u16;
typedef unsigned int u32;
typedef short bf16x8 __attribute__((ext_vector_type(8)));
typedef float f32x16 __attribute__((ext_vector_type(16)));

__device__ __forceinline__ float b2f(u16 u) { return __uint_as_float(((u32)u) << 16); }
__device__ __forceinline__ u16 f2b(float f) {
    u32 x = __float_as_uint(f);
    u32 lsb = (x >> 16) & 1u;
    return (u16)((x + 0x7fffu + lsb) >> 16);
}

// stub symbol kept
__global__ void HeteroGATLayer_14259291423309_kernel() {}

// ---------------- setup: zero gcur + zij constants ----------------
struct SetupP {
    int* gcur;
    const float* attn[3]; const float* fcW[3]; const float* fcb[3];
    float* consts;
};

__global__ __launch_bounds__(256) void k_setup(SetupP p) {
    const int i = blockIdx.x * 256 + threadIdx.x;
    if (i < NBKT) p.gcur[i] = 0;
    if (blockIdx.x == 3) {
        const int z = threadIdx.x >> 6, lane = threadIdx.x & 63;
        if (z < 3) {
            float a2 = p.attn[z][128 + lane];
            float x = p.fcW[z][lane] * a2;
            float y = p.fcb[z][lane] * a2;
            #pragma unroll
            for (int off = 32; off; off >>= 1) {
                x += __shfl_down(x, off);
                y += __shfl_down(y, off);
            }
            if (lane == 0) {
                // consts slots by g': g'0 temporal -> 0,1 ; g'4 ttr -> 8,9 ; g'1 rut -> 2,3
                const int co[3] = {0, 8, 2};
                p.consts[co[z]] = x;
                p.consts[co[z] + 1] = y;
            }
        }
    }
}

// ---------------- projections via MFMA + fused attention dots ----------------
struct ProjP {
    const float* feat[3];
    const float* W[8]; const float* b[8];
    u16* wh;                    // Wh arena base
    int ntile[3]; int tiles[3][4];
    int nvec[8];
    const float* avec[8][4];    // attention sub-vector (64 floats)
    float* dvec[8][4];          // destination (el/er + g'*NN)
};

__global__ __launch_bounds__(256) void k_proj(ProjP p) {
    __shared__ u16 sA[64 * 64];      // feat tile (persistent)
    __shared__ u16 sW[64 * 64];      // weight tile
    __shared__ u16 sC[64 * 66];      // C tile, padded stride
    const int f = blockIdx.y;
    const int tid = threadIdx.x;
    const int row0 = blockIdx.x * 64;
    const float* feat = p.feat[f];

    #pragma unroll
    for (int q = 0; q < 4; ++q) {
        int idx = q * 256 + tid;
        int r = idx >> 4;
        int c4 = (idx & 15) * 4;
        int gr = row0 + r;
        if (gr >= NN) gr = NN - 1;
        float4 fv = *(const float4*)(feat + (size_t)gr * 64 + c4);
        *(ushort4*)&sA[r * 64 + c4] = make_ushort4(f2b(fv.x), f2b(fv.y), f2b(fv.z), f2b(fv.w));
    }

    const int wv = tid >> 6, lane = tid & 63;
    const int mrow = (wv & 1) * 32, ncol = (wv >> 1) * 32;
    const int half = lane >> 5, l31 = lane & 31;
    const int nt = p.ntile[f];

    for (int ti = 0; ti < nt; ++ti) {
        const int t = p.tiles[f][ti];
        const float* W = p.W[t];
        #pragma unroll
        for (int q = 0; q < 4; ++q) {
            int idx = q * 256 + tid;
            int r = idx >> 4;
            int c4 = (idx & 15) * 4;
            float4 wv4 = *(const float4*)(W + r * 64 + c4);
            *(ushort4*)&sW[r * 64 + c4] = make_ushort4(f2b(wv4.x), f2b(wv4.y), f2b(wv4.z), f2b(wv4.w));
        }
        __syncthreads();    // sA/sW staged; prev iteration's dots (sC reads) done

        f32x16 acc;
        #pragma unroll
        for (int i = 0; i < 16; ++i) acc[i] = 0.0f;
        #pragma unroll
        for (int k0 = 0; k0 < 64; k0 += 16) {
            bf16x8 af = *(const bf16x8*)&sA[(mrow + l31) * 64 + k0 + half * 8];
            bf16x8 bf = *(const bf16x8*)&sW[(ncol + l31) * 64 + k0 + half * 8];
            acc = __builtin_amdgcn_mfma_f32_32x32x16_bf16(af, bf, acc, 0, 0, 0);
        }

        float bb = p.b[t][ncol + l31];
        u16* whp = p.wh + (size_t)t * NN * 64;
        #pragma unroll
        for (int reg = 0; reg < 16; ++reg) {
            int rowD = (reg & 3) + 8 * (reg >> 2) + 4 * half;
            int gr = row0 + mrow + rowD;
            u16 c16 = f2b(acc[reg] + bb);
            if (gr < NN) whp[(size_t)gr * 64 + ncol + l31] = c16;
            sC[(mrow + rowD) * 66 + ncol + l31] = c16;
        }
        __syncthreads();    // sC complete

        // fused attention dots: thread = (row r, vec j); 64 FMA each
        const int r = tid & 63, j = tid >> 6;
        if (j < p.nvec[t]) {
            const float* av = p.avec[t][j];
            float s = 0.f;
            #pragma unroll
            for (int c = 0; c < 64; c += 4) {
                ushort4 cv = *(const ushort4*)&sC[r * 66 + c];
                float4 a4 = *(const float4*)(av + c);
                s += b2f(cv.x) * a4.x + b2f(cv.y) * a4.y + b2f(cv.z) * a4.z + b2f(cv.w) * a4.w;
            }
            int gr = row0 + r;
            if (gr < NN) p.dvec[t][j][gr] = s;
        }
    }
}

// ---------------- binA: etype-PAIR LDS-histogram binning, key = dst*8+g' ----------------
// grid (293, 4): blockIdx.y = etype pair -> 1172 blocks (vs 293 fused-8) for occupancy;
// 2048 edges/block keeps ~2.6-slot write clustering per bucket.
// payload: {arena byte off of src Wh row, f32 raw exp score, f32 sc*w, (dst&63)*8+g}
struct BinAP {
    const int* src[8]; const int* dst[8]; const float* w[8];
    const float* el[8]; const float* er[8];
    const float* consts;
    int whoff[8];
    int* gcur; int4* bkt;
};

__global__ __launch_bounds__(512) void k_binA(BinAP p) {
    __shared__ int hist[784];
    const int tid = threadIdx.x;
    const int gp0 = blockIdx.y * 2;              // this block: etypes gp0, gp0+1
    const int e = blockIdx.x * TILE + tid * 2;   // 2 edges/thread/etype
    for (int i = tid; i < 784; i += 512) hist[i] = 0;
    const bool valid = e < EE;                   // EE even -> e+1 also in range
    int d0[2], d1[2];
    __syncthreads();
    // phase A: histogram over 782 buckets (2 etypes), keep dst in regs
    #pragma unroll
    for (int gi = 0; gi < 2; ++gi) {
        int2 dv = valid ? *(const int2*)(p.dst[gp0 + gi] + e) : make_int2(0, 0);
        d0[gi] = dv.x; d1[gi] = dv.y;
        if (valid) {
            atomicAdd(&hist[dv.x >> 6], 1);
            atomicAdd(&hist[dv.y >> 6], 1);
        }
    }
    __syncthreads();
    // phase B: one global atomic per (block,bucket); hist becomes write cursor
    for (int b = tid; b < NBKT; b += 512) {
        int c = hist[b];
        hist[b] = c ? atomicAdd(&p.gcur[b], c) : 0;
    }
    __syncthreads();
    // phase C: payload + clustered write
    #pragma unroll
    for (int gi = 0; gi < 2; ++gi) {
        if (!valid) continue;
        const int g = gp0 + gi;
        int2 sv = *(const int2*)(p.src[g] + e);
        const float* wp = p.w[g];
        const bool hw = wp != 0;
        float2 wv = hw ? *(const float2*)(wp + e) : make_float2(0.f, 0.f);
        float c1 = 0.f, c0 = 0.f;
        if (g < 7 && hw) { c1 = p.consts[2 * g]; c0 = p.consts[2 * g + 1]; }
        const int wo = p.whoff[g];
        int ss[2] = {sv.x, sv.y};
        int dd[2] = {d0[gi], d1[gi]};
        float ww[2] = {wv.x, wv.y};
        #pragma unroll
        for (int q = 0; q < 2; ++q) {
            float sc = 1.0f, pw = 0.0f;
            if (g < 7) {
                sc = p.el[g][ss[q]] + p.er[g][dd[q]];
                if (hw) sc += c1 * ww[q] + c0;
                sc = sc > 0.f ? sc : 0.2f * sc;       // leaky_relu(0.2)
                sc = __expf(sc);
                if (hw) pw = sc * ww[q];
            }
            int bkt_i = dd[q] >> 6;
            int pos = atomicAdd(&hist[bkt_i], 1);
            int4 v;
            v.x = wo + (ss[q] << 7);
            v.y = __float_as_int(sc);
            v.z = __float_as_int(pw);
            v.w = ((dd[q] & 63) << 3) | g;
            p.bkt[(size_t)bkt_i * BCAP + pos] = v;
        }
    }
}

// ---------------- bg: fused counting sort + softmax + gather + ReLU + output ------------
// bucket = 64 nodes x 8 gats. After sort, node n's slots are contiguous per target:
// task = keys n8..n8+1, worker = n8+2..n8+4, state = n8+5..n8+7 (g' ordering).
struct BgP {
    const float* fcW[3]; const float* fcb[3];   // 0: temporal fc, 1: ttr fc, 2: rut fc
};

// masked 4-slot step: slots beyond len contribute 0 (off masked to row 0, alpha to 0)
#define BGSTEP4(t, baseV, lenV)                                                    \
    {                                                                              \
        int2 e0 = st2[baseV + k], e1 = st2[baseV + k + 1];                         \
        int2 e2 = st2[baseV + k + 2], e3 = st2[baseV + k + 3];                     \
        int o0 = (k < lenV) ? e0.x : 0;                                            \
        int o1 = (k + 1 < lenV) ? e1.x : 0;                                        \
        int o2 = (k + 2 < lenV) ? e2.x : 0;                                        \
        int o3 = (k + 3 < lenV) ? e3.x : 0;                                        \
        float f0 = (k < lenV) ? __int_as_float(e0.y) : 0.f;                        \
        float f1 = (k + 1 < lenV) ? __int_as_float(e1.y) : 0.f;                    \
        float f2 = (k + 2 < lenV) ? __int_as_float(e2.y) : 0.f;                    \
        float f3 = (k + 3 < lenV) ? __int_as_float(e3.y) : 0.f;                    \
        u32 w0 = *(const u32*)(whA + (u32)(o0 + dby));                             \
        u32 w1 = *(const u32*)(whA + (u32)(o1 + dby));                             \
        u32 w2 = *(const u32*)(whA + (u32)(o2 + dby));                             \
        u32 w3 = *(const u32*)(whA + (u32)(o3 + dby));                             \
        a0[t] += f0 * b2f((u16)w0); a1[t] += f0 * b2f((u16)(w0 >> 16));            \
        a0[t] += f1 * b2f((u16)w1); a1[t] += f1 * b2f((u16)(w1 >> 16));            \
        a0[t] += f2 * b2f((u16)w2); a1[t] += f2 * b2f((u16)(w2 >> 16));            \
        a0[t] += f3 * b2f((u16)w3); a1[t] += f3 * b2f((u16)(w3 >> 16));            \
    }

__global__ __launch_bounds__(512) void k_bg(BgP p, const int* __restrict__ gcur,
        const int4* __restrict__ bkt, const char* __restrict__ whA,
        float* __restrict__ out) {
    __shared__ int2 st2[BCAP + 128];   // sorted {arena_off, alpha}; +128 masked-read pad
    __shared__ float st3[BCAP];        // sorted pw
    __shared__ int hist[512];
    __shared__ int scn[512];
    __shared__ float sSw[512];
    __shared__ int wsum[8];
    const int b = blockIdx.x;
    const int tid = threadIdx.x;
    int count = gcur[b];
    if (count > BCAP) count = BCAP;
    hist[tid] = 0;
    __syncthreads();
    const int4* src = bkt + (size_t)b * BCAP;
    for (int i = tid; i < count; i += 512) atomicAdd(&hist[src[i].w], 1);
    __syncthreads();
    // shuffle-based exclusive scan of 512 counts
    int h = hist[tid];
    const int lane = tid & 63, wvi = tid >> 6;
    int incl = h;
    #pragma unroll
    for (int off = 1; off < 64; off <<= 1) {
        int t = __shfl_up(incl, off);
        if (lane >= off) incl += t;
    }
    if (lane == 63) wsum[wvi] = incl;
    __syncthreads();
    int wb = 0;
    #pragma unroll
    for (int w = 0; w < 8; ++w)
        if (w < wvi) wb += wsum[w];
    const int excl = wb + incl - h;
    scn[tid] = excl;
    __syncthreads();
    // scatter sorted into LDS
    for (int i = tid; i < count; i += 512) {
        int4 v = src[i];
        int pos = atomicAdd(&scn[v.w], 1);
        st2[pos] = make_int2(v.x, v.y);
        st3[pos] = __int_as_float(v.z);
    }
    __syncthreads();
    // per-key: den/sw sums, then pre-scale alpha = sc * inv in place (own segment)
    float den = 0.f, sw = 0.f;
    for (int j = 0; j < h; ++j) {
        den += __int_as_float(st2[excl + j].y);
        sw += st3[excl + j];
    }
    const int gk = tid & 7;
    float inv = (gk == 7) ? 1.0f : ((h > 0 && den > 0.f) ? 1.0f / den : 0.f);
    sSw[tid] = sw * inv;
    for (int j = 0; j < h; ++j)
        st2[excl + j].y = __float_as_int(__int_as_float(st2[excl + j].y) * inv);
    __syncthreads();
    // gather: 8 waves x 2 nodes/wave x 4 passes = 64 nodes
    const int half = lane >> 5, c = lane & 31;
    const int dby = c * 4;
    for (int pass = 0; pass < 4; ++pass) {
        const int nl = pass * 16 + wvi * 2 + half;
        const int n8 = nl * 8;
        // per-target contiguous ranges (scn post-scatter = segment end)
        int bT = scn[n8] - hist[n8];
        int eT = scn[n8 + 1];
        int eW = scn[n8 + 4];
        int eS = scn[n8 + 7];
        int lT = eT - bT, lW = eW - eT, lS = eS - eW;
        int lTa = __builtin_amdgcn_readlane(lT, 0), lTb = __builtin_amdgcn_readlane(lT, 32);
        int lWa = __builtin_amdgcn_readlane(lW, 0), lWb = __builtin_amdgcn_readlane(lW, 32);
        int lSa = __builtin_amdgcn_readlane(lS, 0), lSb = __builtin_amdgcn_readlane(lS, 32);
        int lTm = lTa > lTb ? lTa : lTb;
        int lWm = lWa > lWb ? lWa : lWb;
        int lSm = lSa > lSb ? lSa : lSb;
        int kmax = lTm > lWm ? lTm : lWm;
        kmax = kmax > lSm ? kmax : lSm;

        float a0[3] = {0.f, 0.f, 0.f}, a1[3] = {0.f, 0.f, 0.f};
        for (int k = 0; k < kmax; k += 4) {
            if (k < lTm) BGSTEP4(0, bT, lT)
            if (k < lWm) BGSTEP4(1, eT, lW)
            if (k < lSm) BGSTEP4(2, eW, lS)
        }

        float tT0 = a0[0], tT1 = a1[0];
        if (hist[n8] > 0) {        // temporal fc
            float2 fw = *(const float2*)(p.fcW[0] + 2 * c);
            float2 fb = *(const float2*)(p.fcb[0] + 2 * c);
            float s = sSw[n8];
            tT0 += fw.x * s + fb.x; tT1 += fw.y * s + fb.y;
        }
        if (hist[n8 + 1] > 0) {    // rut fc
            float2 fw = *(const float2*)(p.fcW[2] + 2 * c);
            float2 fb = *(const float2*)(p.fcb[2] + 2 * c);
            float s = sSw[n8 + 1];
            tT0 += fw.x * s + fb.x; tT1 += fw.y * s + fb.y;
        }
        float tW0 = a0[1], tW1 = a1[1];
        if (hist[n8 + 4] > 0) {    // ttr fc
            float2 fw = *(const float2*)(p.fcW[1] + 2 * c);
            float2 fb = *(const float2*)(p.fcb[1] + 2 * c);
            float s = sSw[n8 + 4];
            tW0 += fw.x * s + fb.x; tW1 += fw.y * s + fb.y;
        }
        float tS0 = a0[2], tS1 = a1[2];

        const int gnode = b * 64 + nl;
        if (gnode < NN) {
            float2 o;
            o.x = tT0 > 0.f ? tT0 : 0.f; o.y = tT1 > 0.f ? tT1 : 0.f;
            *(float2*)(out + ((size_t)0 * NN + gnode) * 64 + 2 * c) = o;
            o.x = tW0 > 0.f ? tW0 : 0.f; o.y = tW1 > 0.f ? tW1 : 0.f;
            *(float2*)(out + ((size_t)1 * NN + gnode) * 64 + 2 * c) = o;
            o.x = tS0 > 0.f ? tS0 : 0.f; o.y = tS1 > 0.f ? tS1 : 0.f;
            *(float2*)(out + ((size_t)2 * NN + gnode) * 64 + 2 * c) = o;
        }
    }
}

extern "C" void kernel_launch(void* const* d_in, const int* in_sizes, int n_in,
                              void* d_out, int out_size, void* d_ws, size_t ws_size,
                              hipStream_t stream) {
    (void)in_sizes; (void)n_in; (void)out_size; (void)ws_size;
    const float* feats[3] = {(const float*)d_in[0], (const float*)d_in[1], (const float*)d_in[2]};
    const int* srcs[8];
    const int* dsts[8];
    for (int t = 0; t < 8; ++t) {
        srcs[t] = (const int*)d_in[3 + 2 * t];
        dsts[t] = (const int*)d_in[4 + 2 * t];
    }
    const float* ew0 = (const float*)d_in[19];
    const float* ew1 = (const float*)d_in[20];
    const float* ew2 = (const float*)d_in[21];
    const float* Wm[8];
    const float* bm[8];
    for (int t = 0; t < 8; ++t) {
        Wm[t] = (const float*)d_in[22 + 2 * t];
        bm[t] = (const float*)d_in[23 + 2 * t];
    }
    const float* fcW0 = (const float*)d_in[38];
    const float* fcb0 = (const float*)d_in[39];
    const float* fcW1 = (const float*)d_in[40];
    const float* fcb1 = (const float*)d_in[41];
    const float* fcW2 = (const float*)d_in[42];
    const float* fcb2 = (const float*)d_in[43];
    const float* attn_W          = (const float*)d_in[44];
    const float* attn_ttr_W      = (const float*)d_in[45];
    const float* attn_rut_W      = (const float*)d_in[46];
    const float* attn_assigned_W = (const float*)d_in[47];
    const float* attn_com_W      = (const float*)d_in[48];
    const float* attn_tin_W      = (const float*)d_in[49];
    const float* attn_rin_W      = (const float*)d_in[50];

    // ---- workspace (~100 MB): Wh 51.2 | el/er 2.8 | consts | gcur | bkt 44.8
    u16* Wh = (u16*)d_ws;
    char* b0 = (char*)d_ws + (size_t)8 * NN * 64 * sizeof(u16);
    float* el     = (float*)b0;
    float* er     = el + (size_t)7 * NN;
    float* consts = er + (size_t)7 * NN;
    int* gcur     = (int*)(consts + 16);
    int4* bkt     = (int4*)(((size_t)(gcur + NBKT) + 15) & ~(size_t)15);

    // g' order (target-contiguous): 0 temporal, 1 rut | 2 assigned, 3 com, 4 ttr |
    //                               5 tin, 6 win, 7 sin
    int g_et[8]   = {0, 7, 1, 2, 6, 3, 4, 5};    // etype index per g'
    int g_sidx[8] = {0, 7, 1, 2, 6, 3, 4, 5};    // src Wh tile per g'
    const float* g_w[8] = {ew0, ew2, 0, 0, ew1, 0, 0, 0};

    // 1) setup: zero gcur + zij constants
    {
        SetupP sp;
        sp.gcur = gcur;
        sp.attn[0] = attn_W;     sp.fcW[0] = fcW0; sp.fcb[0] = fcb0;
        sp.attn[1] = attn_ttr_W; sp.fcW[1] = fcW1; sp.fcb[1] = fcb1;
        sp.attn[2] = attn_rut_W; sp.fcW[2] = fcW2; sp.fcb[2] = fcb2;
        sp.consts = consts;
        k_setup<<<4, 256, 0, stream>>>(sp);
    }

    // 2) projections (MFMA) + fused el/er dots (el/er indexed by g')
    {
        ProjP pp;
        pp.feat[0] = feats[0]; pp.feat[1] = feats[1]; pp.feat[2] = feats[2];
        for (int t = 0; t < 8; ++t) { pp.W[t] = Wm[t]; pp.b[t] = bm[t]; }
        pp.wh = Wh;
        pp.ntile[0] = 4; pp.tiles[0][0] = 0; pp.tiles[0][1] = 1; pp.tiles[0][2] = 3; pp.tiles[0][3] = 6;
        pp.ntile[1] = 3; pp.tiles[1][0] = 2; pp.tiles[1][1] = 4; pp.tiles[1][2] = 7; pp.tiles[1][3] = 0;
        pp.ntile[2] = 1; pp.tiles[2][0] = 5; pp.tiles[2][1] = 0; pp.tiles[2][2] = 0; pp.tiles[2][3] = 0;
        for (int t = 0; t < 8; ++t) {
            pp.nvec[t] = 0;
            for (int j = 0; j < 4; ++j) { pp.avec[t][j] = 0; pp.dvec[t][j] = 0; }
        }
        auto setv = [&](int t, int j, const float* a, float* dv) { pp.avec[t][j] = a; pp.dvec[t][j] = dv; };
        // tile -> dot vectors; el[g'] = src-tile dot, er[g'] = dst-tile dot
        pp.nvec[0] = 3; setv(0, 0, attn_W, el + 0 * NN);            // el g'0
                        setv(0, 1, attn_W + 64, er + 0 * NN);       // er g'0
                        setv(0, 2, attn_rut_W + 64, er + 1 * NN);   // er g'1 (rut dst = task)
        pp.nvec[1] = 1; setv(1, 0, attn_assigned_W, el + 2 * NN);   // el g'2
        pp.nvec[2] = 4; setv(2, 0, attn_com_W, el + 3 * NN);        // el g'3
                        setv(2, 1, attn_assigned_W + 64, er + 2 * NN);
                        setv(2, 2, attn_com_W + 64, er + 3 * NN);
                        setv(2, 3, attn_ttr_W + 64, er + 4 * NN);
        pp.nvec[3] = 1; setv(3, 0, attn_tin_W, el + 5 * NN);        // el g'5
        pp.nvec[4] = 1; setv(4, 0, attn_rin_W, el + 6 * NN);        // el g'6
        pp.nvec[5] = 2; setv(5, 0, attn_tin_W + 64, er + 5 * NN);
                        setv(5, 1, attn_rin_W + 64, er + 6 * NN);
        pp.nvec[6] = 1; setv(6, 0, attn_ttr_W, el + 4 * NN);        // el g'4
        pp.nvec[7] = 1; setv(7, 0, attn_rut_W, el + 1 * NN);        // el g'1
        k_proj<<<dim3(782, 3), 256, 0, stream>>>(pp);
    }

    // 3) binA: bucketed payload build, 2 etypes per block (grid y = pair)
    {
        BinAP bp;
        for (int g = 0; g < 8; ++g) {
            bp.src[g] = srcs[g_et[g]];
            bp.dst[g] = dsts[g_et[g]];
            bp.w[g] = g_w[g];
            bp.el[g] = (g < 7) ? el + (size_t)g * NN : 0;
            bp.er[g] = (g < 7) ? er + (size_t)g * NN : 0;
            bp.whoff[g] = g_sidx[g] * NN * 128;     // byte offset of gat's Wh tile
        }
        bp.consts = consts;
        bp.gcur = gcur;
        bp.bkt = bkt;
        k_binA<<<dim3(NBLKE, 4), 512, 0, stream>>>(bp);
    }

    // 4) bg: fused sort + softmax + gather + ReLU + output
    {
        BgP gp;
        gp.fcW[0] = fcW0; gp.fcb[0] = fcb0;
        gp.fcW[1] = fcW1; gp.fcb[1] = fcb1;
        gp.fcW[2] = fcW2; gp.fcb[2] = fcb2;
        k_bg<<<NBKT, 512, 0, stream>>>(gp, gcur, bkt, (const char*)Wh, (float*)d_out);
    }
}

// Round 13
// 352.697 us; speedup vs baseline: 1.1020x; 1.0992x over previous
//
#include <hip/hip_runtime.h>
#include <math.h>

#define NN 50000
#define EE 300000
#define NG 8                   // 7 softmax GATs + 1 plain (sin)
#define NTOT (NG * NN)         // 400000 keys
#define NBKT 782               // buckets of 512 (gat,node) keys
#define BCAP 3584              // slots per bucket (mean 3072, sigma~55 -> 9 sigma margin)
#define TILE 1024              // edges per binA block
#define NBLKE ((EE + TILE - 1) / TILE)   // 293

typedef unsigned short u16;
typedef unsigned int u32;
typedef unsigned long long u64;
typedef short bf16x8 __attribute__((ext_vector_type(8)));
typedef float f32x16 __attribute__((ext_vector_type(16)));

__device__ __forceinline__ float b2f(u16 u) { return __uint_as_float(((u32)u) << 16); }
__device__ __forceinline__ u16 f2b(float f) {
    u32 x = __float_as_uint(f);
    u32 lsb = (x >> 16) & 1u;
    return (u16)((x + 0x7fffu + lsb) >> 16);
}

// stub symbol kept
__global__ void HeteroGATLayer_14259291423309_kernel() {}

// ---------------- setup: zero gcur + zij constants (1 launch) ----------------
struct SetupP {
    int* gcur;
    const float* attn[3]; const float* fcW[3]; const float* fcb[3];
    float* consts;
};

__global__ __launch_bounds__(256) void k_setup(SetupP p) {
    const int i = blockIdx.x * 256 + threadIdx.x;
    if (i < NBKT) p.gcur[i] = 0;
    if (blockIdx.x == 3) {
        const int z = threadIdx.x >> 6, lane = threadIdx.x & 63;
        if (z < 3) {
            float a2 = p.attn[z][128 + lane];
            float x = p.fcW[z][lane] * a2;
            float y = p.fcb[z][lane] * a2;
            #pragma unroll
            for (int off = 32; off; off >>= 1) {
                x += __shfl_down(x, off);
                y += __shfl_down(y, off);
            }
            if (lane == 0) {
                const int co[3] = {0, 10, 12};   // g=0 (temporal), g=5 (ttr), g=6 (rut)
                p.consts[co[z]] = x;
                p.consts[co[z] + 1] = y;
            }
        }
    }
}

// ---------------- projections via MFMA + fused attention dots ----------------
struct ProjP {
    const float* feat[3];
    const float* W[8]; const float* b[8];
    u16* wh;                    // Wh arena base
    int ntile[3]; int tiles[3][4];
    int nvec[8];
    const float* avec[8][4];    // attention sub-vector (64 floats)
    float* dvec[8][4];          // destination (el/er + g*NN)
};

__global__ __launch_bounds__(256) void k_proj(ProjP p) {
    __shared__ u16 sA[64 * 64];      // feat tile (persistent)
    __shared__ u16 sW[64 * 64];      // weight tile
    __shared__ u16 sC[64 * 66];      // C tile, padded stride
    const int f = blockIdx.y;
    const int tid = threadIdx.x;
    const int row0 = blockIdx.x * 64;
    const float* feat = p.feat[f];

    #pragma unroll
    for (int q = 0; q < 4; ++q) {
        int idx = q * 256 + tid;
        int r = idx >> 4;
        int c4 = (idx & 15) * 4;
        int gr = row0 + r;
        if (gr >= NN) gr = NN - 1;
        float4 fv = *(const float4*)(feat + (size_t)gr * 64 + c4);
        *(ushort4*)&sA[r * 64 + c4] = make_ushort4(f2b(fv.x), f2b(fv.y), f2b(fv.z), f2b(fv.w));
    }

    const int wv = tid >> 6, lane = tid & 63;
    const int mrow = (wv & 1) * 32, ncol = (wv >> 1) * 32;
    const int half = lane >> 5, l31 = lane & 31;
    const int nt = p.ntile[f];

    for (int ti = 0; ti < nt; ++ti) {
        const int t = p.tiles[f][ti];
        const float* W = p.W[t];
        #pragma unroll
        for (int q = 0; q < 4; ++q) {
            int idx = q * 256 + tid;
            int r = idx >> 4;
            int c4 = (idx & 15) * 4;
            float4 wv4 = *(const float4*)(W + r * 64 + c4);
            *(ushort4*)&sW[r * 64 + c4] = make_ushort4(f2b(wv4.x), f2b(wv4.y), f2b(wv4.z), f2b(wv4.w));
        }
        __syncthreads();    // sA/sW staged; prev iteration's dots (sC reads) done

        f32x16 acc;
        #pragma unroll
        for (int i = 0; i < 16; ++i) acc[i] = 0.0f;
        #pragma unroll
        for (int k0 = 0; k0 < 64; k0 += 16) {
            bf16x8 af = *(const bf16x8*)&sA[(mrow + l31) * 64 + k0 + half * 8];
            bf16x8 bf = *(const bf16x8*)&sW[(ncol + l31) * 64 + k0 + half * 8];
            acc = __builtin_amdgcn_mfma_f32_32x32x16_bf16(af, bf, acc, 0, 0, 0);
        }

        float bb = p.b[t][ncol + l31];
        u16* whp = p.wh + (size_t)t * NN * 64;
        #pragma unroll
        for (int reg = 0; reg < 16; ++reg) {
            int rowD = (reg & 3) + 8 * (reg >> 2) + 4 * half;
            int gr = row0 + mrow + rowD;
            u16 c16 = f2b(acc[reg] + bb);
            if (gr < NN) whp[(size_t)gr * 64 + ncol + l31] = c16;
            sC[(mrow + rowD) * 66 + ncol + l31] = c16;
        }
        __syncthreads();    // sC complete

        // fused attention dots: thread = (row r, vec j); 64 FMA each
        const int r = tid & 63, j = tid >> 6;
        if (j < p.nvec[t]) {
            const float* av = p.avec[t][j];
            float s = 0.f;
            #pragma unroll
            for (int c = 0; c < 64; c += 4) {
                ushort4 cv = *(const ushort4*)&sC[r * 66 + c];
                float4 a4 = *(const float4*)(av + c);
                s += b2f(cv.x) * a4.x + b2f(cv.y) * a4.y + b2f(cv.z) * a4.z + b2f(cv.w) * a4.w;
            }
            int gr = row0 + r;
            if (gr < NN) p.dvec[t][j][gr] = s;
        }
    }
}

// ---------------- binA: g-major LDS-histogram binning (clustered bucket writes) ---------
// payload: {arena byte offset of src Wh row, f32 raw exp score, f32 sc*w, key&511}
struct BinAP {
    const int* src[8]; const int* dst[8]; const float* w[8];
    const float* el[8]; const float* er[8];
    const float* consts;
    int whoff[8];
    int* gcur; int4* bkt;
};

__global__ __launch_bounds__(256) void k_binA(BinAP p) {
    __shared__ int hist[128];
    const int g = blockIdx.y;
    const int b0 = (g * NN) >> 9;          // first bucket this g can touch
    const int tid = threadIdx.x;
    const int e = blockIdx.x * TILE + tid * 4;
    if (tid < 128) hist[tid] = 0;

    const bool hw = p.w[g] != 0;
    float c1 = 0.f, c0 = 0.f;
    if (g < 7 && hw) { c1 = p.consts[2 * g]; c0 = p.consts[2 * g + 1]; }
    const int wo = p.whoff[g];

    // phase 0: load 4 edges (coalesced 16B/lane) + compute payload into regs
    int sr[4], bl[4], low[4];
    float sc[4], pw[4];
    const bool valid = e < EE;             // EE%4==0 -> whole int4 in range
    if (valid) {
        int4 s4 = *(const int4*)(p.src[g] + e);
        int4 d4 = *(const int4*)(p.dst[g] + e);
        float4 w4 = make_float4(0.f, 0.f, 0.f, 0.f);
        if (hw) w4 = *(const float4*)(p.w[g] + e);
        int ss[4] = {s4.x, s4.y, s4.z, s4.w};
        int dd[4] = {d4.x, d4.y, d4.z, d4.w};
        float ww[4] = {w4.x, w4.y, w4.z, w4.w};
        #pragma unroll
        for (int q = 0; q < 4; ++q) {
            int key = g * NN + dd[q];
            bl[q] = (key >> 9) - b0;       // local bucket idx, <= 98
            low[q] = key & 511;
            sr[q] = wo + (ss[q] << 7);     // arena byte offset of Wh row
            float scv = 1.0f, pwv = 0.0f;
            if (g < 7) {
                scv = p.el[g][ss[q]] + p.er[g][dd[q]];
                if (hw) scv += c1 * ww[q] + c0;
                scv = scv > 0.f ? scv : 0.2f * scv;   // leaky_relu(0.2)
                scv = __expf(scv);
                if (hw) pwv = scv * ww[q];
            }
            sc[q] = scv; pw[q] = pwv;
        }
    }
    __syncthreads();                       // hist zero visible
    // phase 1: LDS histogram
    if (valid) {
        #pragma unroll
        for (int q = 0; q < 4; ++q) atomicAdd(&hist[bl[q]], 1);
    }
    __syncthreads();
    // phase 2: one global atomic per (block,bucket); hist becomes write cursor
    if (tid < 128) {
        int c = hist[tid];
        hist[tid] = c ? atomicAdd(&p.gcur[b0 + tid], c) : 0;
    }
    __syncthreads();
    // phase 3: clustered payload write at globally-reserved positions
    if (valid) {
        #pragma unroll
        for (int q = 0; q < 4; ++q) {
            int pos = atomicAdd(&hist[bl[q]], 1);
            int4 v;
            v.x = sr[q];
            v.y = __float_as_int(sc[q]);
            v.z = __float_as_int(pw[q]);
            v.w = low[q];
            p.bkt[(size_t)(b0 + bl[q]) * BCAP + pos] = v;
        }
    }
}

// ---------------- binB: counting sort in LDS + atomic-free segment sums -----------------
// csr slot (coalesced write): {arena_off, f32 raw sc}
// rowdeg4 per key: {(beg<<10)|deg, f32 inv_den, f32 scw*inv, 0}
__global__ __launch_bounds__(512) void k_binB(const int* __restrict__ gcur,
                                              const int4* __restrict__ bkt,
                                              int2* __restrict__ csr,
                                              int4* __restrict__ rowdeg) {
    __shared__ int2 st2[BCAP];       // 28.7 KB sorted {off, sc}
    __shared__ float st3[BCAP];      // 14.3 KB sorted pw
    __shared__ int hist[512];
    __shared__ int scn[512];
    __shared__ int wsum[8];
    const int b = blockIdx.x;
    const int tid = threadIdx.x;
    int count = gcur[b];
    if (count > BCAP) count = BCAP;
    hist[tid] = 0;
    __syncthreads();
    const int4* src = bkt + (size_t)b * BCAP;
    // pass 1: histogram (global read; L2-hot for pass 2)
    for (int i = tid; i < count; i += 512) atomicAdd(&hist[src[i].w], 1);
    __syncthreads();
    // shuffle-based exclusive scan of 512 counts (3 barriers total)
    int h = hist[tid];
    const int lane = tid & 63, wvi = tid >> 6;
    int incl = h;
    #pragma unroll
    for (int off = 1; off < 64; off <<= 1) {
        int t = __shfl_up(incl, off);
        if (lane >= off) incl += t;
    }
    if (lane == 63) wsum[wvi] = incl;
    __syncthreads();
    int wb = 0;
    #pragma unroll
    for (int w = 0; w < 8; ++w)
        if (w < wvi) wb += wsum[w];
    const int excl = wb + incl - h;
    scn[tid] = excl;
    __syncthreads();
    // pass 2: scatter sorted into LDS
    for (int i = tid; i < count; i += 512) {
        int4 v = src[i];
        int pos = atomicAdd(&scn[v.w], 1);
        st2[pos] = make_int2(v.x, v.y);
        st3[pos] = __int_as_float(v.z);
    }
    __syncthreads();
    // per-key serial segment sums (no atomics, ~deg=6 iters)
    float den = 0.f, sw = 0.f;
    for (int j = 0; j < h; ++j) {
        den += __int_as_float(st2[excl + j].y);
        sw += st3[excl + j];
    }
    const int gkey = b * 512 + tid;
    if (gkey < NTOT) {
        float inv = (gkey >= 7 * NN) ? 1.0f : ((h > 0 && den > 0.f) ? 1.0f / den : 0.f);
        u32 beg = (u32)(b * BCAP + excl);
        rowdeg[gkey] = make_int4((int)((beg << 10) | (u32)h),
                                 __float_as_int(inv), __float_as_int(sw * inv), 0);
    }
    // coalesced sorted csr write
    for (int i = tid; i < count; i += 512) csr[(size_t)b * BCAP + i] = st2[i];
}

// ---------------- gather: 4 nodes per wave (4 groups x 16 lanes x ushort4) --------------
// One u64 global load instruction covers FOUR edges (4 rows x 128B); 12 edge chains
// + 12 accumulator sets in flight per wave at the same occupancy.
struct GathP {
    int gidx[3][3]; int hasfc[3][3];
    const float* fcW[3][3]; const float* fcb[3][3];
};

// one slot-step of gat t at slot k: per-group uniform LDS read (broadcast within
// 16-lane group, 4 distinct addrs per instruction), u64 row load, 4 FMA per lane.
#define GSLOT(t, kk)                                                               \
    {                                                                              \
        int2 e = sSeg[wv][t][gn][kk];                                              \
        u64 w = *(const u64*)(whA + (u32)(e.x + dby));                             \
        float al = __int_as_float(e.y);                                            \
        a0[t] += al * b2f((u16)w);                                                 \
        a1[t] += al * b2f((u16)(w >> 16));                                         \
        a2[t] += al * b2f((u16)(w >> 32));                                         \
        a3[t] += al * b2f((u16)(w >> 48));                                         \
    }

#define GSTEP4(t)                                                                  \
    { GSLOT(t, k) GSLOT(t, k + 1) GSLOT(t, k + 2) GSLOT(t, k + 3) }

__global__ __launch_bounds__(256) void k_gather(GathP p,
        const int4* __restrict__ rowdeg, const int2* __restrict__ csr,
        const char* __restrict__ whA, float* __restrict__ out) {
    __shared__ int2 sSeg[4][3][4][64];           // 24 KB: [wave][gat][group][slot]
    const int tg = blockIdx.y;
    const int wv = threadIdx.x >> 6, lane = threadIdx.x & 63;
    const int gn = lane >> 4, c16 = lane & 15;   // node group, column quad
    const int i = blockIdx.x * 16 + wv * 4 + gn; // NN = 3125*16 exactly
    const int dby = c16 * 8;                     // byte offset of ushort4 within row
    const int ng = (tg == 0) ? 2 : 3;            // task target has only 2 gats

    // per-lane descriptors (uniform within 16-lane group)
    int lenv[3]; u32 begv[3]; float invv[3], swv[3];
    #pragma unroll
    for (int t = 0; t < 3; ++t) {
        lenv[t] = 0; begv[t] = 0; invv[t] = 0.f; swv[t] = 0.f;
        if (t < ng) {
            int4 rv = rowdeg[p.gidx[tg][t] * NN + i];
            lenv[t] = rv.x & 1023;
            begv[t] = ((u32)rv.x) >> 10;
            invv[t] = __int_as_float(rv.y);
            swv[t] = __int_as_float(rv.z);
        }
    }
    // scalar per-group lens/begs for staging + loop bounds
    int lenG[3][4]; u32 begG[3][4]; int lmax[3];
    #pragma unroll
    for (int t = 0; t < 3; ++t) {
        #pragma unroll
        for (int gg = 0; gg < 4; ++gg) {
            lenG[t][gg] = __builtin_amdgcn_readlane(lenv[t], gg * 16);
            begG[t][gg] = (u32)__builtin_amdgcn_readlane((int)begv[t], gg * 16);
        }
        int m01 = lenG[t][0] > lenG[t][1] ? lenG[t][0] : lenG[t][1];
        int m23 = lenG[t][2] > lenG[t][3] ? lenG[t][2] : lenG[t][3];
        lmax[t] = m01 > m23 ? m01 : m23;
    }
    int kall = lmax[0] > lmax[1] ? lmax[0] : lmax[1];
    kall = kall > lmax[2] ? kall : lmax[2];

    float a0[3] = {0.f, 0.f, 0.f}, a1[3] = {0.f, 0.f, 0.f};
    float a2[3] = {0.f, 0.f, 0.f}, a3[3] = {0.f, 0.f, 0.f};
    for (int cb = 0; cb < kall; cb += 64) {      // single chunk unless deg > 64
        // stage chunk (all gats, all 4 groups; slots >= len hold {0,0})
        #pragma unroll
        for (int t = 0; t < 3; ++t) {
            if (cb < lmax[t]) {
                #pragma unroll
                for (int gg = 0; gg < 4; ++gg) {
                    int rem = lenG[t][gg] - cb;
                    int2 v = (lane < rem) ? csr[begG[t][gg] + cb + lane] : make_int2(0, 0);
                    sSeg[wv][t][gg][lane] = v;
                }
            }
        }
        // wave-synchronous: no barrier for own wave's slice
        int l0 = lmax[0] - cb, l1 = lmax[1] - cb, l2 = lmax[2] - cb;
        if (l0 > 64) l0 = 64;
        if (l1 > 64) l1 = 64;
        if (l2 > 64) l2 = 64;
        int cmax = l0 > l1 ? l0 : l1;
        cmax = cmax > l2 ? cmax : l2;
        for (int k = 0; k < cmax; k += 4) {
            if (k < l0) GSTEP4(0)
            if (k < l1) GSTEP4(1)
            if (k < l2) GSTEP4(2)
        }
    }

    float t0 = 0.f, t1 = 0.f, t2 = 0.f, t3 = 0.f;
    #pragma unroll
    for (int t = 0; t < 3; ++t) {
        t0 += a0[t] * invv[t];                   // invv==0 when deg==0
        t1 += a1[t] * invv[t];
        t2 += a2[t] * invv[t];
        t3 += a3[t] * invv[t];
        if (p.hasfc[tg][t]) {
            bool he = lenv[t] > 0;               // fc term only when node has edges
            float4 fw = *(const float4*)(p.fcW[tg][t] + 4 * c16);
            float4 fb = *(const float4*)(p.fcb[tg][t] + 4 * c16);
            float s = swv[t];
            t0 += he ? (fw.x * s + fb.x) : 0.f;
            t1 += he ? (fw.y * s + fb.y) : 0.f;
            t2 += he ? (fw.z * s + fb.z) : 0.f;
            t3 += he ? (fw.w * s + fb.w) : 0.f;
        }
    }
    float4 o;
    o.x = t0 > 0.f ? t0 : 0.f;
    o.y = t1 > 0.f ? t1 : 0.f;
    o.z = t2 > 0.f ? t2 : 0.f;
    o.w = t3 > 0.f ? t3 : 0.f;
    *(float4*)(out + ((size_t)tg * NN + i) * 64 + 4 * c16) = o;
}

extern "C" void kernel_launch(void* const* d_in, const int* in_sizes, int n_in,
                              void* d_out, int out_size, void* d_ws, size_t ws_size,
                              hipStream_t stream) {
    (void)in_sizes; (void)n_in; (void)out_size; (void)ws_size;
    const float* feats[3] = {(const float*)d_in[0], (const float*)d_in[1], (const float*)d_in[2]};
    const int* srcs[8];
    const int* dsts[8];
    for (int t = 0; t < 8; ++t) {
        srcs[t] = (const int*)d_in[3 + 2 * t];
        dsts[t] = (const int*)d_in[4 + 2 * t];
    }
    const float* ew0 = (const float*)d_in[19];
    const float* ew1 = (const float*)d_in[20];
    const float* ew2 = (const float*)d_in[21];
    const float* Wm[8];
    const float* bm[8];
    for (int t = 0; t < 8; ++t) {
        Wm[t] = (const float*)d_in[22 + 2 * t];
        bm[t] = (const float*)d_in[23 + 2 * t];
    }
    const float* fcW0 = (const float*)d_in[38];
    const float* fcb0 = (const float*)d_in[39];
    const float* fcW1 = (const float*)d_in[40];
    const float* fcb1 = (const float*)d_in[41];
    const float* fcW2 = (const float*)d_in[42];
    const float* fcb2 = (const float*)d_in[43];
    const float* attn_W          = (const float*)d_in[44];
    const float* attn_ttr_W      = (const float*)d_in[45];
    const float* attn_rut_W      = (const float*)d_in[46];
    const float* attn_assigned_W = (const float*)d_in[47];
    const float* attn_com_W      = (const float*)d_in[48];
    const float* attn_tin_W      = (const float*)d_in[49];
    const float* attn_rin_W      = (const float*)d_in[50];

    // ---- workspace (~128 MB): Wh 51.2 | el/er 2.8 | consts | gcur | rowdeg4 6.4 |
    //                           bkt 44.8 | csr 22.4
    u16* Wh = (u16*)d_ws;
    char* b0 = (char*)d_ws + (size_t)8 * NN * 64 * sizeof(u16);
    float* el     = (float*)b0;
    float* er     = el + (size_t)7 * NN;
    float* consts = er + (size_t)7 * NN;
    int* gcur     = (int*)(consts + 16);
    int4* rowdeg4 = (int4*)(((size_t)(gcur + NBKT) + 15) & ~(size_t)15);
    int4* bkt     = rowdeg4 + NTOT;
    int2* csr     = (int2*)(bkt + (size_t)NBKT * BCAP);

    int g_et[8]   = {0, 1, 2, 3, 4, 6, 7, 5};
    int g_sidx[8] = {0, 1, 2, 3, 4, 6, 7, 5};
    const float* g_w[8] = {ew0, 0, 0, 0, 0, ew1, ew2, 0};

    // 1) setup: zero gcur + zij constants (single launch)
    {
        SetupP sp;
        sp.gcur = gcur;
        sp.attn[0] = attn_W;     sp.fcW[0] = fcW0; sp.fcb[0] = fcb0;
        sp.attn[1] = attn_ttr_W; sp.fcW[1] = fcW1; sp.fcb[1] = fcb1;
        sp.attn[2] = attn_rut_W; sp.fcW[2] = fcW2; sp.fcb[2] = fcb2;
        sp.consts = consts;
        k_setup<<<4, 256, 0, stream>>>(sp);
    }

    // 2) projections (MFMA) + fused el/er dots
    {
        ProjP pp;
        pp.feat[0] = feats[0]; pp.feat[1] = feats[1]; pp.feat[2] = feats[2];
        for (int t = 0; t < 8; ++t) { pp.W[t] = Wm[t]; pp.b[t] = bm[t]; }
        pp.wh = Wh;
        pp.ntile[0] = 4; pp.tiles[0][0] = 0; pp.tiles[0][1] = 1; pp.tiles[0][2] = 3; pp.tiles[0][3] = 6;
        pp.ntile[1] = 3; pp.tiles[1][0] = 2; pp.tiles[1][1] = 4; pp.tiles[1][2] = 7; pp.tiles[1][3] = 0;
        pp.ntile[2] = 1; pp.tiles[2][0] = 5; pp.tiles[2][1] = 0; pp.tiles[2][2] = 0; pp.tiles[2][3] = 0;
        for (int t = 0; t < 8; ++t) {
            pp.nvec[t] = 0;
            for (int j = 0; j < 4; ++j) { pp.avec[t][j] = 0; pp.dvec[t][j] = 0; }
        }
        auto setv = [&](int t, int j, const float* a, float* dv) { pp.avec[t][j] = a; pp.dvec[t][j] = dv; };
        // tile -> el/er dot vectors (el[g] from tile sidx[g], er[g] from tile didx[g])
        pp.nvec[0] = 3; setv(0, 0, attn_W, el);           setv(0, 1, attn_W + 64, er);
                        setv(0, 2, attn_rut_W + 64, er + 6 * NN);
        pp.nvec[1] = 1; setv(1, 0, attn_assigned_W, el + 1 * NN);
        pp.nvec[2] = 4; setv(2, 0, attn_com_W, el + 2 * NN); setv(2, 1, attn_assigned_W + 64, er + 1 * NN);
                        setv(2, 2, attn_com_W + 64, er + 2 * NN); setv(2, 3, attn_ttr_W + 64, er + 5 * NN);
        pp.nvec[3] = 1; setv(3, 0, attn_tin_W, el + 3 * NN);
        pp.nvec[4] = 1; setv(4, 0, attn_rin_W, el + 4 * NN);
        pp.nvec[5] = 2; setv(5, 0, attn_tin_W + 64, er + 3 * NN); setv(5, 1, attn_rin_W + 64, er + 4 * NN);
        pp.nvec[6] = 1; setv(6, 0, attn_ttr_W, el + 5 * NN);
        pp.nvec[7] = 1; setv(7, 0, attn_rut_W, el + 6 * NN);
        k_proj<<<dim3(782, 3), 256, 0, stream>>>(pp);
    }

    // 3) bucketed CSR build: binA (g-major clustered writes) -> binB (sort + segment sums)
    {
        BinAP bp;
        for (int g = 0; g < 8; ++g) {
            bp.src[g] = srcs[g_et[g]];
            bp.dst[g] = dsts[g_et[g]];
            bp.w[g] = g_w[g];
            bp.el[g] = (g < 7) ? el + (size_t)g * NN : 0;
            bp.er[g] = (g < 7) ? er + (size_t)g * NN : 0;
            bp.whoff[g] = g_sidx[g] * NN * 128;     // byte offset of gat's Wh tile
        }
        bp.consts = consts;
        bp.gcur = gcur;
        bp.bkt = bkt;
        k_binA<<<dim3(NBLKE, 8), 256, 0, stream>>>(bp);
    }
    k_binB<<<NBKT, 512, 0, stream>>>(gcur, bkt, csr, rowdeg4);

    // 4) gather (single launch; 4 nodes/wave, 16 nodes/block)
    {
        GathP gp;
        // task: temporal (fc) + rut (fc)  [ng=2]
        gp.gidx[0][0] = 0; gp.hasfc[0][0] = 1; gp.fcW[0][0] = fcW0; gp.fcb[0][0] = fcb0;
        gp.gidx[0][1] = 6; gp.hasfc[0][1] = 1; gp.fcW[0][1] = fcW2; gp.fcb[0][1] = fcb2;
        gp.gidx[0][2] = 0; gp.hasfc[0][2] = 0; gp.fcW[0][2] = fcW0; gp.fcb[0][2] = fcb0;
        // worker: assigned + com + ttr (fc)
        gp.gidx[1][0] = 1; gp.hasfc[1][0] = 0; gp.fcW[1][0] = fcW0; gp.fcb[1][0] = fcb0;
        gp.gidx[1][1] = 2; gp.hasfc[1][1] = 0; gp.fcW[1][1] = fcW0; gp.fcb[1][1] = fcb0;
        gp.gidx[1][2] = 5; gp.hasfc[1][2] = 1; gp.fcW[1][2] = fcW1; gp.fcb[1][2] = fcb1;
        // state: tin + win + sin (sin: inv=1 plain sum)
        gp.gidx[2][0] = 3; gp.hasfc[2][0] = 0; gp.fcW[2][0] = fcW0; gp.fcb[2][0] = fcb0;
        gp.gidx[2][1] = 4; gp.hasfc[2][1] = 0; gp.fcW[2][1] = fcW0; gp.fcb[2][1] = fcb0;
        gp.gidx[2][2] = 7; gp.hasfc[2][2] = 0; gp.fcW[2][2] = fcW0; gp.fcb[2][2] = fcb0;
        k_gather<<<dim3(NN / 16, 3), 256, 0, stream>>>(gp, rowdeg4, csr,
                                                       (const char*)Wh, (float*)d_out);
    }
}